// Round 7
// baseline (914.651 us; speedup 1.0000x reference)
//
#include <hip/hip_runtime.h>
#include <cstdint>
#include <cstddef>

#define FDIM 128
#define SLICES 8     // feature slices (1 per XCD); 16 features = 32 B each
#define SW 16
#define CHUNK 4096   // edges per binning chunk
#define BSHIFT 8     // 256 nodes per bucket
#define BMASK 255
#define MAXB 512     // max buckets supported (N <= 131072)

typedef unsigned short ushort_t;
typedef __attribute__((ext_vector_type(8))) short short8;   // 8 bf16 (4 VGPRs)
typedef __attribute__((ext_vector_type(4))) float floatx4;  // MFMA C/D

// bf16 helpers (bit-level, RTN-even).
__device__ inline ushort_t f2bf(float f) {
  unsigned u = __float_as_uint(f);
  u += 0x7fffu + ((u >> 16) & 1u);
  return (ushort_t)(u >> 16);
}
__device__ inline float bf2f(ushort_t h) {
  return __uint_as_float((unsigned)h << 16);
}

// ---------------- CSR build (bucketed) ----------------

__global__ __launch_bounds__(256) void k_hist(const int* __restrict__ dst, int e,
                                              int nb, int* __restrict__ chunkHist) {
  __shared__ int h[MAXB];
  int c = blockIdx.x;
  int base = c * CHUNK;
  int end = min(base + CHUNK, e);
  for (int i = threadIdx.x; i < nb; i += 256) h[i] = 0;
  __syncthreads();
  for (int i = base + threadIdx.x; i < end; i += 256)
    atomicAdd(&h[dst[i] >> BSHIFT], 1);
  __syncthreads();
  for (int b = threadIdx.x; b < nb; b += 256)
    chunkHist[(size_t)c * nb + b] = h[b];
}

// Per-bucket scan over the chunk axis (one block per bucket).
__global__ __launch_bounds__(512) void k_scan1(const int* __restrict__ chunkHist,
                                               int nchunks, int nb,
                                               int* __restrict__ chunkOff,
                                               int* __restrict__ bucketTotal) {
  __shared__ int sb[512];
  int b = blockIdx.x;
  int t = threadIdx.x;
  int base = 0;
  for (int c0 = 0; c0 < nchunks; c0 += 512) {
    int c = c0 + t;
    int v = (c < nchunks) ? chunkHist[(size_t)c * nb + b] : 0;
    int x = v;
    sb[t] = x;
    __syncthreads();
    for (int off = 1; off < 512; off <<= 1) {
      int y = (t >= off) ? sb[t - off] : 0;
      __syncthreads();
      x += y;
      sb[t] = x;
      __syncthreads();
    }
    if (c < nchunks) chunkOff[(size_t)c * nb + b] = base + x - v;
    int tileTot = sb[511];
    __syncthreads();
    base += tileTot;
  }
  if (t == 0) bucketTotal[b] = base;
}

__global__ __launch_bounds__(512) void k_scan2(const int* __restrict__ bucketTotal,
                                               int nb, int e,
                                               int* __restrict__ bucketBase) {
  __shared__ int sb[512];
  int t = threadIdx.x;
  int v = (t < nb) ? bucketTotal[t] : 0;
  int x = v;
  sb[t] = x;
  __syncthreads();
  for (int off = 1; off < 512; off <<= 1) {
    int y = (t >= off) ? sb[t - off] : 0;
    __syncthreads();
    x += y;
    sb[t] = x;
    __syncthreads();
  }
  if (t < nb) bucketBase[t] = x - v;
  if (t == 0) bucketBase[nb] = e;
}

__global__ __launch_bounds__(256) void k_bin(const int* __restrict__ src,
                                             const int* __restrict__ dst, int e, int nb,
                                             const int* __restrict__ chunkHist,
                                             const int* __restrict__ chunkOff,
                                             const int* __restrict__ bucketBase,
                                             unsigned* __restrict__ binned) {
  __shared__ unsigned sortedL[CHUNK];
  __shared__ int gtarget[CHUNK];
  __shared__ int lbase[MAXB], lcur[MAXB], gbase[MAXB];
  __shared__ int stmp[256];
  int c = blockIdx.x;
  int base = c * CHUNK;
  int end = min(base + CHUNK, e);
  for (int i = threadIdx.x; i < nb; i += 256) {
    lbase[i] = chunkHist[(size_t)c * nb + i];  // temp: counts
    gbase[i] = bucketBase[i] + chunkOff[(size_t)c * nb + i];
  }
  __syncthreads();
  int carry = 0;
  for (int i0 = 0; i0 < nb; i0 += 256) {
    int i = i0 + threadIdx.x;
    int v = (i < nb) ? lbase[i] : 0;
    int x = v;
    stmp[threadIdx.x] = x;
    __syncthreads();
    for (int off = 1; off < 256; off <<= 1) {
      int y = (threadIdx.x >= off) ? stmp[threadIdx.x - off] : 0;
      __syncthreads();
      x += y;
      stmp[threadIdx.x] = x;
      __syncthreads();
    }
    if (i < nb) lbase[i] = carry + x - v;
    int tileTot = stmp[255];
    __syncthreads();
    carry += tileTot;
  }
  for (int i = threadIdx.x; i < nb; i += 256) lcur[i] = lbase[i];
  __syncthreads();
  for (int i = base + threadIdx.x; i < end; i += 256) {
    int d = dst[i];
    int sv = src[i];
    int b = d >> BSHIFT;
    int slot = atomicAdd(&lcur[b], 1);
    sortedL[slot] = ((unsigned)sv << BSHIFT) | (unsigned)(d & BMASK);
    gtarget[slot] = gbase[b] + (slot - lbase[b]);
  }
  __syncthreads();
  for (int i = threadIdx.x; i < end - base; i += 256)
    binned[gtarget[i]] = sortedL[i];
}

__global__ __launch_bounds__(256) void k_fill2(const unsigned* __restrict__ binned,
                                               const int* __restrict__ bucketBase, int n,
                                               int* __restrict__ rowStart,
                                               int* __restrict__ deg,
                                               float* __restrict__ dis,
                                               int* __restrict__ colIdx) {
  __shared__ int h[256], sb[256], cur[256];
  int b = blockIdx.x;
  int s0 = bucketBase[b], s1 = bucketBase[b + 1];
  int nodeBase = b << BSHIFT;
  int t = threadIdx.x;
  h[t] = 0;
  __syncthreads();
  for (int i = s0 + t; i < s1; i += 256) atomicAdd(&h[binned[i] & BMASK], 1);
  __syncthreads();
  int v = h[t];
  int x = v;
  sb[t] = x;
  __syncthreads();
  for (int off = 1; off < 256; off <<= 1) {
    int y = (t >= off) ? sb[t - off] : 0;
    __syncthreads();
    x += y;
    sb[t] = x;
    __syncthreads();
  }
  int start = s0 + x - v;
  cur[t] = start;
  int node = nodeBase + t;
  if (node < n) {
    rowStart[node] = start;
    deg[node] = v;
    dis[node] = rsqrtf((float)(v + 1));  // +1 self-loop
  }
  __syncthreads();
  for (int i = s0 + t; i < s1; i += 256) {
    unsigned en = binned[i];
    int slot = atomicAdd(&cur[en & BMASK], 1);
    colIdx[slot] = (int)(en >> BSHIFT);
  }
}

// ---------------- W prep: fp32 -> bf16, swizzled into B-fragment order ----
__global__ __launch_bounds__(256) void k_prepw(const float* __restrict__ W1,
                                               const float* __restrict__ W2,
                                               const float* __restrict__ W3,
                                               ushort_t* __restrict__ out) {
  int b = blockIdx.x;
  const float* W = (b == 0) ? W1 : (b == 1) ? W2 : W3;
  ushort_t* o = out + (size_t)b * 16384;
  for (int idx = threadIdx.x; idx < 16384; idx += 256) {
    int j = idx & 7;
    int lane = (idx >> 3) & 63;
    int ct = (idx >> 9) & 7;
    int kc = idx >> 12;
    int k = kc * 32 + (lane >> 4) * 8 + j;
    int col = ct * 16 + (lane & 15);
    o[idx] = f2bf(W[k * FDIM + col]);
  }
}

// ---------------- MFMA matmul ----------------
// H tensors are SLICE-MAJOR: Hs[slice][node][16] bf16 (slice = feature/16).
// A-frag k-range kc*32+quad*8..+7 lies inside one slice; output cols ct*16+l15
// lie inside slice ct. fp32 x input (layer 1) is row-major.
template <int INBF>
__global__ __launch_bounds__(256) void k_mm(const void* __restrict__ Ain,
                                            const ushort_t* __restrict__ Wsw,
                                            ushort_t* __restrict__ O, int n) {
  __shared__ ushort_t Bs[16384];  // 32 KB
  int tid = threadIdx.x;
  for (int q = tid; q < 2048; q += 256)
    ((uint4*)Bs)[q] = ((const uint4*)Wsw)[q];
  __syncthreads();

  int w = tid >> 6;
  int lane = tid & 63;
  int quad = lane >> 4;
  int l15 = lane & 15;
  int rb = blockIdx.x * 128 + w * 32;
  const float* Af = (const float*)Ain;
  const ushort_t* Ab = (const ushort_t*)Ain;

  int row0 = rb + l15;
  int row1 = rb + 16 + l15;
  bool v0 = row0 < n, v1 = row1 < n;

  floatx4 acc[2][8];
#pragma unroll
  for (int rt = 0; rt < 2; ++rt)
#pragma unroll
    for (int ct = 0; ct < 8; ++ct) acc[rt][ct] = floatx4{0.f, 0.f, 0.f, 0.f};

#pragma unroll
  for (int kc = 0; kc < 4; ++kc) {
    int k0 = kc * 32 + quad * 8;
    short8 a0 = short8{0, 0, 0, 0, 0, 0, 0, 0};
    short8 a1 = short8{0, 0, 0, 0, 0, 0, 0, 0};
    if (INBF) {
      int sl = k0 >> 4, of = k0 & 15;  // slice-major address
      if (v0) a0 = *(const short8*)&Ab[((size_t)sl * n + row0) * SW + of];
      if (v1) a1 = *(const short8*)&Ab[((size_t)sl * n + row1) * SW + of];
    } else {
      if (v0) {
        float4 f0 = *(const float4*)&Af[(size_t)row0 * FDIM + k0];
        float4 f1 = *(const float4*)&Af[(size_t)row0 * FDIM + k0 + 4];
        a0 = short8{(short)f2bf(f0.x), (short)f2bf(f0.y), (short)f2bf(f0.z),
                    (short)f2bf(f0.w), (short)f2bf(f1.x), (short)f2bf(f1.y),
                    (short)f2bf(f1.z), (short)f2bf(f1.w)};
      }
      if (v1) {
        float4 f0 = *(const float4*)&Af[(size_t)row1 * FDIM + k0];
        float4 f1 = *(const float4*)&Af[(size_t)row1 * FDIM + k0 + 4];
        a1 = short8{(short)f2bf(f0.x), (short)f2bf(f0.y), (short)f2bf(f0.z),
                    (short)f2bf(f0.w), (short)f2bf(f1.x), (short)f2bf(f1.y),
                    (short)f2bf(f1.z), (short)f2bf(f1.w)};
      }
    }
#pragma unroll
    for (int ct = 0; ct < 8; ++ct) {
      short8 bf = *(const short8*)&Bs[((kc * 8 + ct) * 64 + lane) * 8];
      acc[0][ct] = __builtin_amdgcn_mfma_f32_16x16x32_bf16(a0, bf, acc[0][ct], 0, 0, 0);
      acc[1][ct] = __builtin_amdgcn_mfma_f32_16x16x32_bf16(a1, bf, acc[1][ct], 0, 0, 0);
    }
  }

#pragma unroll
  for (int rt = 0; rt < 2; ++rt) {
#pragma unroll
    for (int i = 0; i < 4; ++i) {
      int row = rb + rt * 16 + quad * 4 + i;
      if (row < n) {
#pragma unroll
        for (int ct = 0; ct < 8; ++ct)
          O[((size_t)ct * n + row) * SW + l15] = f2bf(acc[rt][ct][i]);
      }
    }
  }
}

// ---------------- aggregation (pull) + bias + ReLU, slice-major bf16 ------
// slice = blockIdx & 7 -> all blocks of slice s land on XCD s (round-robin
// workgroup dispatch heuristic): per-XCD gather working set = 3.2 MB slice,
// L2-resident. Wave = 8 edge-groups x 8 lanes; 8 edges/iteration; xor-shuffle
// reduce (8/16/32) across groups.
__global__ __launch_bounds__(256) void k_agg(const ushort_t* __restrict__ Hin,
                                             ushort_t* __restrict__ Hout,
                                             const int* __restrict__ rowStart,
                                             const int* __restrict__ degE,
                                             const int* __restrict__ colIdx,
                                             const float* __restrict__ dis,
                                             const float* __restrict__ bias, int n) {
  int slice = blockIdx.x & 7;
  int g = blockIdx.x >> 3;
  int wave = threadIdx.x >> 6;
  int lane = threadIdx.x & 63;
  int eg = lane >> 3;  // edge group 0..7
  int f = lane & 7;    // uint (=2 features) within slice
  const unsigned* hin = (const unsigned*)Hin + (size_t)slice * n * 8;
  unsigned* hout = (unsigned*)Hout + (size_t)slice * n * 8;
  float2 bv = ((const float2*)bias)[slice * 8 + f];

  int node0 = (g * 4 + wave) * 8;  // 8 nodes per wave
  for (int ni = 0; ni < 8; ++ni) {
    int node = node0 + ni;
    if (node >= n) return;
    float di = dis[node];
    int s0 = rowStart[node], cnt = degE[node];
    unsigned us = hin[(size_t)node * 8 + f];
    float ws = (eg == 0) ? di * di : 0.f;
    float ax = ws * __uint_as_float(us << 16);
    float ay = ws * __uint_as_float(us & 0xffff0000u);
    for (int j = eg; j < cnt; j += 8) {
      int s = colIdx[s0 + j];
      float w = di * dis[s];
      unsigned u = hin[(size_t)s * 8 + f];
      ax += w * __uint_as_float(u << 16);
      ay += w * __uint_as_float(u & 0xffff0000u);
    }
    ax += __shfl_xor(ax, 8);
    ay += __shfl_xor(ay, 8);
    ax += __shfl_xor(ax, 16);
    ay += __shfl_xor(ay, 16);
    ax += __shfl_xor(ax, 32);
    ay += __shfl_xor(ay, 32);
    if (eg == 0) {
      ax = fmaxf(ax + bv.x, 0.f);
      ay = fmaxf(ay + bv.y, 0.f);
      hout[(size_t)node * 8 + f] = (unsigned)f2bf(ax) | ((unsigned)f2bf(ay) << 16);
    }
  }
}

// ---------------- pooling ----------------

__global__ __launch_bounds__(128) void k_gstart(const int* __restrict__ batch, int n,
                                                int g_count, int* __restrict__ gstart) {
  int g = threadIdx.x;
  if (g > g_count) return;
  int lo = 0, hi = n;
  while (lo < hi) {
    int mid = (lo + hi) >> 1;
    if (batch[mid] < g) lo = mid + 1;
    else hi = mid;
  }
  gstart[g] = lo;
}

__global__ __launch_bounds__(128) void k_pool(const ushort_t* __restrict__ H,
                                              const int* __restrict__ gstart,
                                              float* __restrict__ pooled, int g_count,
                                              int n) {
  int g = blockIdx.x >> 4;
  int c = blockIdx.x & 15;
  int sl = threadIdx.x >> 4;  // slice
  int of = threadIdx.x & 15;
  int s = gstart[g], e = gstart[g + 1];
  int len = e - s;
  int chunk = (len + 15) >> 4;
  int ns = s + c * chunk;
  int ne = min(ns + chunk, e);
  float acc = 0.f;
  for (int i = ns; i < ne; ++i)
    acc += bf2f(H[((size_t)sl * n + i) * SW + of]);
  atomicAdd(&pooled[g * FDIM + threadIdx.x], acc);
}

__global__ __launch_bounds__(192) void k_final(const float* __restrict__ pooled,
                                               const int* __restrict__ gstart,
                                               const float* __restrict__ Wc,
                                               const float* __restrict__ bc,
                                               float* __restrict__ out, int g_count) {
  int t = threadIdx.x;
  if (t >= g_count * 3) return;
  int g = t / 3, c = t % 3;
  int cnt = gstart[g + 1] - gstart[g];
  float inv = 1.0f / (float)max(cnt, 1);
  float acc = bc[c];
#pragma unroll 8
  for (int k = 0; k < FDIM; ++k) acc += pooled[g * FDIM + k] * inv * Wc[k * 3 + c];
  out[g * 3 + c] = acc;
}

// ---------------- host ----------------

extern "C" void kernel_launch(void* const* d_in, const int* in_sizes, int n_in,
                              void* d_out, int out_size, void* d_ws, size_t ws_size,
                              hipStream_t stream) {
  const float* x = (const float*)d_in[0];
  const int* edge = (const int*)d_in[1];
  const int* batch = (const int*)d_in[2];
  const float* W1 = (const float*)d_in[3];
  const float* b1 = (const float*)d_in[4];
  const float* W2 = (const float*)d_in[5];
  const float* b2 = (const float*)d_in[6];
  const float* W3 = (const float*)d_in[7];
  const float* b3 = (const float*)d_in[8];
  const float* Wc = (const float*)d_in[9];
  const float* bc = (const float*)d_in[10];
  float* out = (float*)d_out;

  const int N = in_sizes[0] / FDIM;
  const int E = in_sizes[1] / 2;
  const int G = out_size / 3;
  const int* src = edge;
  const int* dst = edge + E;

  const int NCH = (E + CHUNK - 1) / CHUNK;
  const int NB = (N + (1 << BSHIFT) - 1) >> BSHIFT;

  char* ws = (char*)d_ws;
  size_t off = 0;
  auto carve = [&](size_t bytes) -> void* {
    void* p = ws + off;
    off = (off + bytes + 255) & ~(size_t)255;
    return p;
  };
  ushort_t* h0 = (ushort_t*)carve((size_t)N * FDIM * 2);  // slice-major bf16
  ushort_t* h1 = (ushort_t*)carve((size_t)N * FDIM * 2);
  int* colIdx = (int*)carve((size_t)E * 4);
  unsigned* binned = (unsigned*)carve((size_t)E * 4);
  int* chunkHist = (int*)carve((size_t)NCH * NB * 4);
  int* chunkOff = (int*)carve((size_t)NCH * NB * 4);
  int* bucketTotal = (int*)carve((size_t)NB * 4);
  int* bucketBase = (int*)carve((size_t)(NB + 1) * 4);
  int* rowStart = (int*)carve((size_t)N * 4);
  int* deg = (int*)carve((size_t)N * 4);
  float* dis = (float*)carve((size_t)N * 4);
  int* gstart = (int*)carve((size_t)(G + 1) * 4);
  float* pooled = (float*)carve((size_t)G * FDIM * 4);
  ushort_t* wsw = (ushort_t*)carve((size_t)3 * 16384 * 2);  // swizzled bf16 W
  (void)n_in;
  (void)ws_size;

  hipMemsetAsync(pooled, 0, (size_t)G * FDIM * 4, stream);

  k_hist<<<NCH, 256, 0, stream>>>(dst, E, NB, chunkHist);
  k_scan1<<<NB, 512, 0, stream>>>(chunkHist, NCH, NB, chunkOff, bucketTotal);
  k_scan2<<<1, 512, 0, stream>>>(bucketTotal, NB, E, bucketBase);
  k_bin<<<NCH, 256, 0, stream>>>(src, dst, E, NB, chunkHist, chunkOff, bucketBase,
                                 binned);
  k_fill2<<<NB, 256, 0, stream>>>(binned, bucketBase, N, rowStart, deg, dis, colIdx);
  k_prepw<<<3, 256, 0, stream>>>(W1, W2, W3, wsw);

  int mmb = (N + 127) / 128;
  int aggb = ((N + 31) / 32) * 8;  // 32 nodes/block x 8 slices
  k_mm<0><<<mmb, 256, 0, stream>>>(x, wsw, h0, N);
  k_agg<<<aggb, 256, 0, stream>>>(h0, h1, rowStart, deg, colIdx, dis, b1, N);
  k_mm<1><<<mmb, 256, 0, stream>>>(h1, wsw + 16384, h0, N);
  k_agg<<<aggb, 256, 0, stream>>>(h0, h1, rowStart, deg, colIdx, dis, b2, N);
  k_mm<1><<<mmb, 256, 0, stream>>>(h1, wsw + 32768, h0, N);
  k_agg<<<aggb, 256, 0, stream>>>(h0, h1, rowStart, deg, colIdx, dis, b3, N);

  k_gstart<<<1, 128, 0, stream>>>(batch, N, G, gstart);
  k_pool<<<G * 16, 128, 0, stream>>>(h1, gstart, pooled, G, N);
  k_final<<<1, 192, 0, stream>>>(pooled, gstart, Wc, bc, out, G);
}

// Round 8
// 453.545 us; speedup vs baseline: 2.0167x; 2.0167x over previous
//
#include <hip/hip_runtime.h>
#include <cstdint>
#include <cstddef>

#define FDIM 128
#define CHUNK 4096   // edges per binning chunk
#define BSHIFT 8     // 256 nodes per bucket
#define BMASK 255
#define MAXB 512     // max buckets supported (N <= 131072)

typedef unsigned short ushort_t;
typedef __attribute__((ext_vector_type(8))) short short8;   // 8 bf16 (4 VGPRs)
typedef __attribute__((ext_vector_type(4))) float floatx4;  // MFMA C/D

// bf16 helpers (bit-level, RTN-even).
__device__ inline ushort_t f2bf(float f) {
  unsigned u = __float_as_uint(f);
  u += 0x7fffu + ((u >> 16) & 1u);
  return (ushort_t)(u >> 16);
}
__device__ inline float bf2f(ushort_t h) {
  return __uint_as_float((unsigned)h << 16);
}

// ---------------- CSR build (bucketed) ----------------

__global__ __launch_bounds__(256) void k_hist(const int* __restrict__ dst, int e,
                                              int nb, int* __restrict__ chunkHist) {
  __shared__ int h[MAXB];
  int c = blockIdx.x;
  int base = c * CHUNK;
  int end = min(base + CHUNK, e);
  for (int i = threadIdx.x; i < nb; i += 256) h[i] = 0;
  __syncthreads();
  for (int i = base + threadIdx.x; i < end; i += 256)
    atomicAdd(&h[dst[i] >> BSHIFT], 1);
  __syncthreads();
  for (int b = threadIdx.x; b < nb; b += 256)
    chunkHist[(size_t)c * nb + b] = h[b];
}

// Per-bucket scan over the chunk axis (one block per bucket).
__global__ __launch_bounds__(512) void k_scan1(const int* __restrict__ chunkHist,
                                               int nchunks, int nb,
                                               int* __restrict__ chunkOff,
                                               int* __restrict__ bucketTotal) {
  __shared__ int sb[512];
  int b = blockIdx.x;
  int t = threadIdx.x;
  int base = 0;
  for (int c0 = 0; c0 < nchunks; c0 += 512) {
    int c = c0 + t;
    int v = (c < nchunks) ? chunkHist[(size_t)c * nb + b] : 0;
    int x = v;
    sb[t] = x;
    __syncthreads();
    for (int off = 1; off < 512; off <<= 1) {
      int y = (t >= off) ? sb[t - off] : 0;
      __syncthreads();
      x += y;
      sb[t] = x;
      __syncthreads();
    }
    if (c < nchunks) chunkOff[(size_t)c * nb + b] = base + x - v;
    int tileTot = sb[511];
    __syncthreads();
    base += tileTot;
  }
  if (t == 0) bucketTotal[b] = base;
}

__global__ __launch_bounds__(512) void k_scan2(const int* __restrict__ bucketTotal,
                                               int nb, int e,
                                               int* __restrict__ bucketBase) {
  __shared__ int sb[512];
  int t = threadIdx.x;
  int v = (t < nb) ? bucketTotal[t] : 0;
  int x = v;
  sb[t] = x;
  __syncthreads();
  for (int off = 1; off < 512; off <<= 1) {
    int y = (t >= off) ? sb[t - off] : 0;
    __syncthreads();
    x += y;
    sb[t] = x;
    __syncthreads();
  }
  if (t < nb) bucketBase[t] = x - v;
  if (t == 0) bucketBase[nb] = e;
}

__global__ __launch_bounds__(256) void k_bin(const int* __restrict__ src,
                                             const int* __restrict__ dst, int e, int nb,
                                             const int* __restrict__ chunkHist,
                                             const int* __restrict__ chunkOff,
                                             const int* __restrict__ bucketBase,
                                             unsigned* __restrict__ binned) {
  __shared__ unsigned sortedL[CHUNK];
  __shared__ int gtarget[CHUNK];
  __shared__ int lbase[MAXB], lcur[MAXB], gbase[MAXB];
  __shared__ int stmp[256];
  int c = blockIdx.x;
  int base = c * CHUNK;
  int end = min(base + CHUNK, e);
  for (int i = threadIdx.x; i < nb; i += 256) {
    lbase[i] = chunkHist[(size_t)c * nb + i];  // temp: counts
    gbase[i] = bucketBase[i] + chunkOff[(size_t)c * nb + i];
  }
  __syncthreads();
  int carry = 0;
  for (int i0 = 0; i0 < nb; i0 += 256) {
    int i = i0 + threadIdx.x;
    int v = (i < nb) ? lbase[i] : 0;
    int x = v;
    stmp[threadIdx.x] = x;
    __syncthreads();
    for (int off = 1; off < 256; off <<= 1) {
      int y = (threadIdx.x >= off) ? stmp[threadIdx.x - off] : 0;
      __syncthreads();
      x += y;
      stmp[threadIdx.x] = x;
      __syncthreads();
    }
    if (i < nb) lbase[i] = carry + x - v;
    int tileTot = stmp[255];
    __syncthreads();
    carry += tileTot;
  }
  for (int i = threadIdx.x; i < nb; i += 256) lcur[i] = lbase[i];
  __syncthreads();
  for (int i = base + threadIdx.x; i < end; i += 256) {
    int d = dst[i];
    int sv = src[i];
    int b = d >> BSHIFT;
    int slot = atomicAdd(&lcur[b], 1);
    sortedL[slot] = ((unsigned)sv << BSHIFT) | (unsigned)(d & BMASK);
    gtarget[slot] = gbase[b] + (slot - lbase[b]);
  }
  __syncthreads();
  for (int i = threadIdx.x; i < end - base; i += 256)
    binned[gtarget[i]] = sortedL[i];
}

__global__ __launch_bounds__(256) void k_fill2(const unsigned* __restrict__ binned,
                                               const int* __restrict__ bucketBase, int n,
                                               int* __restrict__ rowStart,
                                               int* __restrict__ deg,
                                               float* __restrict__ dis,
                                               int2* __restrict__ colPair) {
  __shared__ int h[256], sb[256], cur[256];
  int b = blockIdx.x;
  int s0 = bucketBase[b], s1 = bucketBase[b + 1];
  int nodeBase = b << BSHIFT;
  int t = threadIdx.x;
  h[t] = 0;
  __syncthreads();
  for (int i = s0 + t; i < s1; i += 256) atomicAdd(&h[binned[i] & BMASK], 1);
  __syncthreads();
  int v = h[t];
  int x = v;
  sb[t] = x;
  __syncthreads();
  for (int off = 1; off < 256; off <<= 1) {
    int y = (t >= off) ? sb[t - off] : 0;
    __syncthreads();
    x += y;
    sb[t] = x;
    __syncthreads();
  }
  int start = s0 + x - v;
  cur[t] = start;
  int node = nodeBase + t;
  if (node < n) {
    rowStart[node] = start;
    deg[node] = v;
    dis[node] = rsqrtf((float)(v + 1));  // +1 self-loop
  }
  __syncthreads();
  for (int i = s0 + t; i < s1; i += 256) {
    unsigned en = binned[i];
    int slot = atomicAdd(&cur[en & BMASK], 1);
    colPair[slot] = int2{(int)(en >> BSHIFT), 0};
  }
}

// Fill colPair[e].y = dis[src] (src random but dis is 400 KB, L2-resident).
// Removes the dependent per-edge per-layer random dis load from k_agg.
__global__ __launch_bounds__(256) void k_edgew(int2* __restrict__ colPair, int e,
                                               const float* __restrict__ dis) {
  int i = blockIdx.x * 256 + threadIdx.x;
  if (i < e) {
    int2 p = colPair[i];
    p.y = __float_as_int(dis[p.x]);
    colPair[i] = p;
  }
}

// ---------------- W prep: fp32 -> bf16, swizzled into B-fragment order ----
__global__ __launch_bounds__(256) void k_prepw(const float* __restrict__ W1,
                                               const float* __restrict__ W2,
                                               const float* __restrict__ W3,
                                               ushort_t* __restrict__ out) {
  int b = blockIdx.x;
  const float* W = (b == 0) ? W1 : (b == 1) ? W2 : W3;
  ushort_t* o = out + (size_t)b * 16384;
  for (int idx = threadIdx.x; idx < 16384; idx += 256) {
    int j = idx & 7;
    int lane = (idx >> 3) & 63;
    int ct = (idx >> 9) & 7;
    int kc = idx >> 12;
    int k = kc * 32 + (lane >> 4) * 8 + j;
    int col = ct * 16 + (lane & 15);
    o[idx] = f2bf(W[k * FDIM + col]);
  }
}

// ---------------- MFMA matmul (row-major H, round-6 proven form) ----------
template <int INBF>
__global__ __launch_bounds__(256) void k_mm(const void* __restrict__ Ain,
                                            const ushort_t* __restrict__ Wsw,
                                            ushort_t* __restrict__ O, int n) {
  __shared__ ushort_t Bs[16384];  // 32 KB
  int tid = threadIdx.x;
  for (int q = tid; q < 2048; q += 256)
    ((uint4*)Bs)[q] = ((const uint4*)Wsw)[q];
  __syncthreads();

  int w = tid >> 6;
  int lane = tid & 63;
  int quad = lane >> 4;
  int l15 = lane & 15;
  int rb = blockIdx.x * 128 + w * 32;
  const float* Af = (const float*)Ain;
  const ushort_t* Ab = (const ushort_t*)Ain;

  int row0 = rb + l15;
  int row1 = rb + 16 + l15;
  bool v0 = row0 < n, v1 = row1 < n;

  floatx4 acc[2][8];
#pragma unroll
  for (int rt = 0; rt < 2; ++rt)
#pragma unroll
    for (int ct = 0; ct < 8; ++ct) acc[rt][ct] = floatx4{0.f, 0.f, 0.f, 0.f};

#pragma unroll
  for (int kc = 0; kc < 4; ++kc) {
    int k0 = kc * 32 + quad * 8;
    short8 a0 = short8{0, 0, 0, 0, 0, 0, 0, 0};
    short8 a1 = short8{0, 0, 0, 0, 0, 0, 0, 0};
    if (INBF) {
      if (v0) a0 = *(const short8*)&Ab[(size_t)row0 * FDIM + k0];
      if (v1) a1 = *(const short8*)&Ab[(size_t)row1 * FDIM + k0];
    } else {
      if (v0) {
        float4 f0 = *(const float4*)&Af[(size_t)row0 * FDIM + k0];
        float4 f1 = *(const float4*)&Af[(size_t)row0 * FDIM + k0 + 4];
        a0 = short8{(short)f2bf(f0.x), (short)f2bf(f0.y), (short)f2bf(f0.z),
                    (short)f2bf(f0.w), (short)f2bf(f1.x), (short)f2bf(f1.y),
                    (short)f2bf(f1.z), (short)f2bf(f1.w)};
      }
      if (v1) {
        float4 f0 = *(const float4*)&Af[(size_t)row1 * FDIM + k0];
        float4 f1 = *(const float4*)&Af[(size_t)row1 * FDIM + k0 + 4];
        a1 = short8{(short)f2bf(f0.x), (short)f2bf(f0.y), (short)f2bf(f0.z),
                    (short)f2bf(f0.w), (short)f2bf(f1.x), (short)f2bf(f1.y),
                    (short)f2bf(f1.z), (short)f2bf(f1.w)};
      }
    }
#pragma unroll
    for (int ct = 0; ct < 8; ++ct) {
      short8 bf = *(const short8*)&Bs[((kc * 8 + ct) * 64 + lane) * 8];
      acc[0][ct] = __builtin_amdgcn_mfma_f32_16x16x32_bf16(a0, bf, acc[0][ct], 0, 0, 0);
      acc[1][ct] = __builtin_amdgcn_mfma_f32_16x16x32_bf16(a1, bf, acc[1][ct], 0, 0, 0);
    }
  }

  // C/D layout: col = lane&15, row = quad*4 + i (within 16x16 tile)
#pragma unroll
  for (int rt = 0; rt < 2; ++rt) {
#pragma unroll
    for (int i = 0; i < 4; ++i) {
      int row = rb + rt * 16 + quad * 4 + i;
      if (row < n) {
#pragma unroll
        for (int ct = 0; ct < 8; ++ct)
          O[(size_t)row * FDIM + ct * 16 + l15] = f2bf(acc[rt][ct][i]);
      }
    }
  }
}

// ---------------- aggregation (pull) + bias + ReLU, row-major bf16 --------
// 2 nodes per wave: 32 lanes x uint2 (8 B) = 256 B row. colPair = (src,
// dis[src]) -> one streaming 8 B load per edge, no dependent dis lookup.
// unroll 4 -> 8 outstanding 256 B gathers per wave.
__global__ __launch_bounds__(256) void k_agg(const ushort_t* __restrict__ Hin,
                                             ushort_t* __restrict__ Hout,
                                             const int* __restrict__ rowStart,
                                             const int* __restrict__ degE,
                                             const int2* __restrict__ colPair,
                                             const float* __restrict__ dis,
                                             const float* __restrict__ bias, int n) {
  int node = blockIdx.x * 8 + (threadIdx.x >> 5);
  int lane = threadIdx.x & 31;  // uint2 index within the 256 B row
  if (node >= n) return;
  const uint2* hin = (const uint2*)Hin;  // row stride 32 uint2
  float di = dis[node];
  uint2 su = hin[(size_t)node * 32 + lane];
  float ws = di * di;
  float a0 = ws * __uint_as_float(su.x << 16);
  float a1 = ws * __uint_as_float(su.x & 0xffff0000u);
  float a2 = ws * __uint_as_float(su.y << 16);
  float a3 = ws * __uint_as_float(su.y & 0xffff0000u);
  int s0 = rowStart[node], cnt = degE[node];
#pragma unroll 4
  for (int j = 0; j < cnt; ++j) {
    int2 p = colPair[s0 + j];
    float w = di * __int_as_float(p.y);
    uint2 u = hin[(size_t)p.x * 32 + lane];
    a0 += w * __uint_as_float(u.x << 16);
    a1 += w * __uint_as_float(u.x & 0xffff0000u);
    a2 += w * __uint_as_float(u.y << 16);
    a3 += w * __uint_as_float(u.y & 0xffff0000u);
  }
  float4 b = ((const float4*)bias)[lane];
  a0 = fmaxf(a0 + b.x, 0.f);
  a1 = fmaxf(a1 + b.y, 0.f);
  a2 = fmaxf(a2 + b.z, 0.f);
  a3 = fmaxf(a3 + b.w, 0.f);
  uint2 o;
  o.x = (unsigned)f2bf(a0) | ((unsigned)f2bf(a1) << 16);
  o.y = (unsigned)f2bf(a2) | ((unsigned)f2bf(a3) << 16);
  ((uint2*)Hout)[(size_t)node * 32 + lane] = o;
}

// ---------------- pooling ----------------

__global__ __launch_bounds__(128) void k_gstart(const int* __restrict__ batch, int n,
                                                int g_count, int* __restrict__ gstart) {
  int g = threadIdx.x;
  if (g > g_count) return;
  int lo = 0, hi = n;
  while (lo < hi) {
    int mid = (lo + hi) >> 1;
    if (batch[mid] < g) lo = mid + 1;
    else hi = mid;
  }
  gstart[g] = lo;
}

__global__ __launch_bounds__(128) void k_pool(const ushort_t* __restrict__ H,
                                              const int* __restrict__ gstart,
                                              float* __restrict__ pooled, int g_count) {
  int g = blockIdx.x >> 4;
  int c = blockIdx.x & 15;
  int s = gstart[g], e = gstart[g + 1];
  int len = e - s;
  int chunk = (len + 15) >> 4;
  int ns = s + c * chunk;
  int ne = min(ns + chunk, e);
  float acc = 0.f;
  for (int i = ns; i < ne; ++i) acc += bf2f(H[(size_t)i * FDIM + threadIdx.x]);
  atomicAdd(&pooled[g * FDIM + threadIdx.x], acc);
}

__global__ __launch_bounds__(192) void k_final(const float* __restrict__ pooled,
                                               const int* __restrict__ gstart,
                                               const float* __restrict__ Wc,
                                               const float* __restrict__ bc,
                                               float* __restrict__ out, int g_count) {
  int t = threadIdx.x;
  if (t >= g_count * 3) return;
  int g = t / 3, c = t % 3;
  int cnt = gstart[g + 1] - gstart[g];
  float inv = 1.0f / (float)max(cnt, 1);
  float acc = bc[c];
#pragma unroll 8
  for (int k = 0; k < FDIM; ++k) acc += pooled[g * FDIM + k] * inv * Wc[k * 3 + c];
  out[g * 3 + c] = acc;
}

// ---------------- host ----------------

extern "C" void kernel_launch(void* const* d_in, const int* in_sizes, int n_in,
                              void* d_out, int out_size, void* d_ws, size_t ws_size,
                              hipStream_t stream) {
  const float* x = (const float*)d_in[0];
  const int* edge = (const int*)d_in[1];
  const int* batch = (const int*)d_in[2];
  const float* W1 = (const float*)d_in[3];
  const float* b1 = (const float*)d_in[4];
  const float* W2 = (const float*)d_in[5];
  const float* b2 = (const float*)d_in[6];
  const float* W3 = (const float*)d_in[7];
  const float* b3 = (const float*)d_in[8];
  const float* Wc = (const float*)d_in[9];
  const float* bc = (const float*)d_in[10];
  float* out = (float*)d_out;

  const int N = in_sizes[0] / FDIM;
  const int E = in_sizes[1] / 2;
  const int G = out_size / 3;
  const int* src = edge;
  const int* dst = edge + E;

  const int NCH = (E + CHUNK - 1) / CHUNK;
  const int NB = (N + (1 << BSHIFT) - 1) >> BSHIFT;

  char* ws = (char*)d_ws;
  size_t off = 0;
  auto carve = [&](size_t bytes) -> void* {
    void* p = ws + off;
    off = (off + bytes + 255) & ~(size_t)255;
    return p;
  };
  ushort_t* h0 = (ushort_t*)carve((size_t)N * FDIM * 2);  // row-major bf16
  ushort_t* h1 = (ushort_t*)carve((size_t)N * FDIM * 2);
  int2* colPair = (int2*)carve((size_t)E * 8);
  unsigned* binned = (unsigned*)carve((size_t)E * 4);
  int* chunkHist = (int*)carve((size_t)NCH * NB * 4);
  int* chunkOff = (int*)carve((size_t)NCH * NB * 4);
  int* bucketTotal = (int*)carve((size_t)NB * 4);
  int* bucketBase = (int*)carve((size_t)(NB + 1) * 4);
  int* rowStart = (int*)carve((size_t)N * 4);
  int* deg = (int*)carve((size_t)N * 4);
  float* dis = (float*)carve((size_t)N * 4);
  int* gstart = (int*)carve((size_t)(G + 1) * 4);
  float* pooled = (float*)carve((size_t)G * FDIM * 4);
  ushort_t* wsw = (ushort_t*)carve((size_t)3 * 16384 * 2);  // swizzled bf16 W
  (void)n_in;
  (void)ws_size;

  hipMemsetAsync(pooled, 0, (size_t)G * FDIM * 4, stream);

  k_hist<<<NCH, 256, 0, stream>>>(dst, E, NB, chunkHist);
  k_scan1<<<NB, 512, 0, stream>>>(chunkHist, NCH, NB, chunkOff, bucketTotal);
  k_scan2<<<1, 512, 0, stream>>>(bucketTotal, NB, E, bucketBase);
  k_bin<<<NCH, 256, 0, stream>>>(src, dst, E, NB, chunkHist, chunkOff, bucketBase,
                                 binned);
  k_fill2<<<NB, 256, 0, stream>>>(binned, bucketBase, N, rowStart, deg, dis, colPair);
  k_edgew<<<(E + 255) / 256, 256, 0, stream>>>(colPair, E, dis);
  k_prepw<<<3, 256, 0, stream>>>(W1, W2, W3, wsw);

  int mmb = (N + 127) / 128;
  int aggb = (N + 7) / 8;
  k_mm<0><<<mmb, 256, 0, stream>>>(x, wsw, h0, N);
  k_agg<<<aggb, 256, 0, stream>>>(h0, h1, rowStart, deg, colPair, dis, b1, N);
  k_mm<1><<<mmb, 256, 0, stream>>>(h1, wsw + 16384, h0, N);
  k_agg<<<aggb, 256, 0, stream>>>(h0, h1, rowStart, deg, colPair, dis, b2, N);
  k_mm<1><<<mmb, 256, 0, stream>>>(h1, wsw + 32768, h0, N);
  k_agg<<<aggb, 256, 0, stream>>>(h0, h1, rowStart, deg, colPair, dis, b3, N);

  k_gstart<<<1, 128, 0, stream>>>(batch, N, G, gstart);
  k_pool<<<G * 16, 128, 0, stream>>>(h1, gstart, pooled, G);
  k_final<<<1, 192, 0, stream>>>(pooled, gstart, Wc, bc, out, G);
}

// Round 9
// 448.194 us; speedup vs baseline: 2.0407x; 1.0119x over previous
//
#include <hip/hip_runtime.h>
#include <cstdint>
#include <cstddef>

#define FDIM 128
#define CHUNK 4096   // edges per binning chunk
#define BSHIFT 8     // 256 nodes per bucket
#define BMASK 255
#define MAXB 512     // max buckets supported (N <= 131072)

typedef unsigned short ushort_t;
typedef __attribute__((ext_vector_type(8))) short short8;   // 8 bf16 (4 VGPRs)
typedef __attribute__((ext_vector_type(4))) float floatx4;  // MFMA C/D

// bf16 helpers (bit-level, RTN-even).
__device__ inline ushort_t f2bf(float f) {
  unsigned u = __float_as_uint(f);
  u += 0x7fffu + ((u >> 16) & 1u);
  return (ushort_t)(u >> 16);
}
__device__ inline float bf2f(ushort_t h) {
  return __uint_as_float((unsigned)h << 16);
}

// ---------------- CSR build (bucketed) ----------------

__global__ __launch_bounds__(256) void k_hist(const int* __restrict__ dst, int e,
                                              int nb, int* __restrict__ chunkHist) {
  __shared__ int h[MAXB];
  int c = blockIdx.x;
  int base = c * CHUNK;
  int end = min(base + CHUNK, e);
  for (int i = threadIdx.x; i < nb; i += 256) h[i] = 0;
  __syncthreads();
  for (int i = base + threadIdx.x; i < end; i += 256)
    atomicAdd(&h[dst[i] >> BSHIFT], 1);
  __syncthreads();
  for (int b = threadIdx.x; b < nb; b += 256)
    chunkHist[(size_t)c * nb + b] = h[b];
}

// Per-bucket scan over the chunk axis (one block per bucket).
__global__ __launch_bounds__(512) void k_scan1(const int* __restrict__ chunkHist,
                                               int nchunks, int nb,
                                               int* __restrict__ chunkOff,
                                               int* __restrict__ bucketTotal) {
  __shared__ int sb[512];
  int b = blockIdx.x;
  int t = threadIdx.x;
  int base = 0;
  for (int c0 = 0; c0 < nchunks; c0 += 512) {
    int c = c0 + t;
    int v = (c < nchunks) ? chunkHist[(size_t)c * nb + b] : 0;
    int x = v;
    sb[t] = x;
    __syncthreads();
    for (int off = 1; off < 512; off <<= 1) {
      int y = (t >= off) ? sb[t - off] : 0;
      __syncthreads();
      x += y;
      sb[t] = x;
      __syncthreads();
    }
    if (c < nchunks) chunkOff[(size_t)c * nb + b] = base + x - v;
    int tileTot = sb[511];
    __syncthreads();
    base += tileTot;
  }
  if (t == 0) bucketTotal[b] = base;
}

__global__ __launch_bounds__(512) void k_scan2(const int* __restrict__ bucketTotal,
                                               int nb, int e,
                                               int* __restrict__ bucketBase) {
  __shared__ int sb[512];
  int t = threadIdx.x;
  int v = (t < nb) ? bucketTotal[t] : 0;
  int x = v;
  sb[t] = x;
  __syncthreads();
  for (int off = 1; off < 512; off <<= 1) {
    int y = (t >= off) ? sb[t - off] : 0;
    __syncthreads();
    x += y;
    sb[t] = x;
    __syncthreads();
  }
  if (t < nb) bucketBase[t] = x - v;
  if (t == 0) bucketBase[nb] = e;
}

__global__ __launch_bounds__(256) void k_bin(const int* __restrict__ src,
                                             const int* __restrict__ dst, int e, int nb,
                                             const int* __restrict__ chunkHist,
                                             const int* __restrict__ chunkOff,
                                             const int* __restrict__ bucketBase,
                                             unsigned* __restrict__ binned) {
  __shared__ unsigned sortedL[CHUNK];
  __shared__ int gtarget[CHUNK];
  __shared__ int lbase[MAXB], lcur[MAXB], gbase[MAXB];
  __shared__ int stmp[256];
  int c = blockIdx.x;
  int base = c * CHUNK;
  int end = min(base + CHUNK, e);
  for (int i = threadIdx.x; i < nb; i += 256) {
    lbase[i] = chunkHist[(size_t)c * nb + i];  // temp: counts
    gbase[i] = bucketBase[i] + chunkOff[(size_t)c * nb + i];
  }
  __syncthreads();
  int carry = 0;
  for (int i0 = 0; i0 < nb; i0 += 256) {
    int i = i0 + threadIdx.x;
    int v = (i < nb) ? lbase[i] : 0;
    int x = v;
    stmp[threadIdx.x] = x;
    __syncthreads();
    for (int off = 1; off < 256; off <<= 1) {
      int y = (threadIdx.x >= off) ? stmp[threadIdx.x - off] : 0;
      __syncthreads();
      x += y;
      stmp[threadIdx.x] = x;
      __syncthreads();
    }
    if (i < nb) lbase[i] = carry + x - v;
    int tileTot = stmp[255];
    __syncthreads();
    carry += tileTot;
  }
  for (int i = threadIdx.x; i < nb; i += 256) lcur[i] = lbase[i];
  __syncthreads();
  for (int i = base + threadIdx.x; i < end; i += 256) {
    int d = dst[i];
    int sv = src[i];
    int b = d >> BSHIFT;
    int slot = atomicAdd(&lcur[b], 1);
    sortedL[slot] = ((unsigned)sv << BSHIFT) | (unsigned)(d & BMASK);
    gtarget[slot] = gbase[b] + (slot - lbase[b]);
  }
  __syncthreads();
  for (int i = threadIdx.x; i < end - base; i += 256)
    binned[gtarget[i]] = sortedL[i];
}

__global__ __launch_bounds__(256) void k_fill2(const unsigned* __restrict__ binned,
                                               const int* __restrict__ bucketBase, int n,
                                               int* __restrict__ rowStart,
                                               int* __restrict__ deg,
                                               float* __restrict__ dis,
                                               int2* __restrict__ colPair) {
  __shared__ int h[256], sb[256], cur[256];
  int b = blockIdx.x;
  int s0 = bucketBase[b], s1 = bucketBase[b + 1];
  int nodeBase = b << BSHIFT;
  int t = threadIdx.x;
  h[t] = 0;
  __syncthreads();
  for (int i = s0 + t; i < s1; i += 256) atomicAdd(&h[binned[i] & BMASK], 1);
  __syncthreads();
  int v = h[t];
  int x = v;
  sb[t] = x;
  __syncthreads();
  for (int off = 1; off < 256; off <<= 1) {
    int y = (t >= off) ? sb[t - off] : 0;
    __syncthreads();
    x += y;
    sb[t] = x;
    __syncthreads();
  }
  int start = s0 + x - v;
  cur[t] = start;
  int node = nodeBase + t;
  if (node < n) {
    rowStart[node] = start;
    deg[node] = v;
    dis[node] = rsqrtf((float)(v + 1));  // +1 self-loop
  }
  __syncthreads();
  for (int i = s0 + t; i < s1; i += 256) {
    unsigned en = binned[i];
    int slot = atomicAdd(&cur[en & BMASK], 1);
    colPair[slot] = int2{(int)(en >> BSHIFT), 0};
  }
}

// Fill colPair[e].y = dis[src] (src random but dis is 400 KB, L2-resident).
__global__ __launch_bounds__(256) void k_edgew(int2* __restrict__ colPair, int e,
                                               const float* __restrict__ dis) {
  int i = blockIdx.x * 256 + threadIdx.x;
  if (i < e) {
    int2 p = colPair[i];
    p.y = __float_as_int(dis[p.x]);
    colPair[i] = p;
  }
}

// ---------------- W prep: fp32 -> bf16, swizzled into B-fragment order ----
// B frag slot (ct, n=lane&15) holds TRUE column (lane&15)*8 + ct, so the C
// epilogue's 8 ct-values per lane are 8 consecutive output columns -> one
// 16 B store per row (was 64 scalar 2 B stores).
__global__ __launch_bounds__(256) void k_prepw(const float* __restrict__ W1,
                                               const float* __restrict__ W2,
                                               const float* __restrict__ W3,
                                               ushort_t* __restrict__ out) {
  int b = blockIdx.x;
  const float* W = (b == 0) ? W1 : (b == 1) ? W2 : W3;
  ushort_t* o = out + (size_t)b * 16384;
  for (int idx = threadIdx.x; idx < 16384; idx += 256) {
    int j = idx & 7;
    int lane = (idx >> 3) & 63;
    int ct = (idx >> 9) & 7;
    int kc = idx >> 12;
    int k = kc * 32 + (lane >> 4) * 8 + j;
    int col = (lane & 15) * 8 + ct;  // column re-map for coalesced C-stores
    o[idx] = f2bf(W[k * FDIM + col]);
  }
}

// ---------------- MFMA matmul (row-major H) ----------
template <int INBF>
__global__ __launch_bounds__(256) void k_mm(const void* __restrict__ Ain,
                                            const ushort_t* __restrict__ Wsw,
                                            ushort_t* __restrict__ O, int n) {
  __shared__ ushort_t Bs[16384];  // 32 KB
  int tid = threadIdx.x;
  for (int q = tid; q < 2048; q += 256)
    ((uint4*)Bs)[q] = ((const uint4*)Wsw)[q];
  __syncthreads();

  int w = tid >> 6;
  int lane = tid & 63;
  int quad = lane >> 4;
  int l15 = lane & 15;
  int rb = blockIdx.x * 128 + w * 32;
  const float* Af = (const float*)Ain;
  const ushort_t* Ab = (const ushort_t*)Ain;

  int row0 = rb + l15;
  int row1 = rb + 16 + l15;
  bool v0 = row0 < n, v1 = row1 < n;

  floatx4 acc[2][8];
#pragma unroll
  for (int rt = 0; rt < 2; ++rt)
#pragma unroll
    for (int ct = 0; ct < 8; ++ct) acc[rt][ct] = floatx4{0.f, 0.f, 0.f, 0.f};

#pragma unroll
  for (int kc = 0; kc < 4; ++kc) {
    int k0 = kc * 32 + quad * 8;
    short8 a0 = short8{0, 0, 0, 0, 0, 0, 0, 0};
    short8 a1 = short8{0, 0, 0, 0, 0, 0, 0, 0};
    if (INBF) {
      if (v0) a0 = *(const short8*)&Ab[(size_t)row0 * FDIM + k0];
      if (v1) a1 = *(const short8*)&Ab[(size_t)row1 * FDIM + k0];
    } else {
      if (v0) {
        float4 f0 = *(const float4*)&Af[(size_t)row0 * FDIM + k0];
        float4 f1 = *(const float4*)&Af[(size_t)row0 * FDIM + k0 + 4];
        a0 = short8{(short)f2bf(f0.x), (short)f2bf(f0.y), (short)f2bf(f0.z),
                    (short)f2bf(f0.w), (short)f2bf(f1.x), (short)f2bf(f1.y),
                    (short)f2bf(f1.z), (short)f2bf(f1.w)};
      }
      if (v1) {
        float4 f0 = *(const float4*)&Af[(size_t)row1 * FDIM + k0];
        float4 f1 = *(const float4*)&Af[(size_t)row1 * FDIM + k0 + 4];
        a1 = short8{(short)f2bf(f0.x), (short)f2bf(f0.y), (short)f2bf(f0.z),
                    (short)f2bf(f0.w), (short)f2bf(f1.x), (short)f2bf(f1.y),
                    (short)f2bf(f1.z), (short)f2bf(f1.w)};
      }
    }
#pragma unroll
    for (int ct = 0; ct < 8; ++ct) {
      short8 bf = *(const short8*)&Bs[((kc * 8 + ct) * 64 + lane) * 8];
      acc[0][ct] = __builtin_amdgcn_mfma_f32_16x16x32_bf16(a0, bf, acc[0][ct], 0, 0, 0);
      acc[1][ct] = __builtin_amdgcn_mfma_f32_16x16x32_bf16(a1, bf, acc[1][ct], 0, 0, 0);
    }
  }

  // acc[rt][ct][i] = O[rb + rt*16 + quad*4 + i][l15*8 + ct]  (true cols,
  // thanks to the k_prepw column re-map) -> pack 8 ct values, one uint4
  // store per row: wave store = 4 rows x 256 B contiguous.
#pragma unroll
  for (int rt = 0; rt < 2; ++rt) {
#pragma unroll
    for (int i = 0; i < 4; ++i) {
      int row = rb + rt * 16 + quad * 4 + i;
      if (row < n) {
        uint4 pk;
        pk.x = (unsigned)f2bf(acc[rt][0][i]) | ((unsigned)f2bf(acc[rt][1][i]) << 16);
        pk.y = (unsigned)f2bf(acc[rt][2][i]) | ((unsigned)f2bf(acc[rt][3][i]) << 16);
        pk.z = (unsigned)f2bf(acc[rt][4][i]) | ((unsigned)f2bf(acc[rt][5][i]) << 16);
        pk.w = (unsigned)f2bf(acc[rt][6][i]) | ((unsigned)f2bf(acc[rt][7][i]) << 16);
        *(uint4*)&O[(size_t)row * FDIM + l15 * 8] = pk;
      }
    }
  }
}

// ---------------- aggregation (pull) + bias + ReLU, row-major bf16 --------
__global__ __launch_bounds__(256) void k_agg(const ushort_t* __restrict__ Hin,
                                             ushort_t* __restrict__ Hout,
                                             const int* __restrict__ rowStart,
                                             const int* __restrict__ degE,
                                             const int2* __restrict__ colPair,
                                             const float* __restrict__ dis,
                                             const float* __restrict__ bias, int n) {
  int node = blockIdx.x * 8 + (threadIdx.x >> 5);
  int lane = threadIdx.x & 31;  // uint2 index within the 256 B row
  if (node >= n) return;
  const uint2* hin = (const uint2*)Hin;  // row stride 32 uint2
  float di = dis[node];
  uint2 su = hin[(size_t)node * 32 + lane];
  float ws = di * di;
  float a0 = ws * __uint_as_float(su.x << 16);
  float a1 = ws * __uint_as_float(su.x & 0xffff0000u);
  float a2 = ws * __uint_as_float(su.y << 16);
  float a3 = ws * __uint_as_float(su.y & 0xffff0000u);
  int s0 = rowStart[node], cnt = degE[node];
#pragma unroll 4
  for (int j = 0; j < cnt; ++j) {
    int2 p = colPair[s0 + j];
    float w = di * __int_as_float(p.y);
    uint2 u = hin[(size_t)p.x * 32 + lane];
    a0 += w * __uint_as_float(u.x << 16);
    a1 += w * __uint_as_float(u.x & 0xffff0000u);
    a2 += w * __uint_as_float(u.y << 16);
    a3 += w * __uint_as_float(u.y & 0xffff0000u);
  }
  float4 b = ((const float4*)bias)[lane];
  a0 = fmaxf(a0 + b.x, 0.f);
  a1 = fmaxf(a1 + b.y, 0.f);
  a2 = fmaxf(a2 + b.z, 0.f);
  a3 = fmaxf(a3 + b.w, 0.f);
  uint2 o;
  o.x = (unsigned)f2bf(a0) | ((unsigned)f2bf(a1) << 16);
  o.y = (unsigned)f2bf(a2) | ((unsigned)f2bf(a3) << 16);
  ((uint2*)Hout)[(size_t)node * 32 + lane] = o;
}

// ---------------- pooling ----------------

__global__ __launch_bounds__(128) void k_gstart(const int* __restrict__ batch, int n,
                                                int g_count, int* __restrict__ gstart) {
  int g = threadIdx.x;
  if (g > g_count) return;
  int lo = 0, hi = n;
  while (lo < hi) {
    int mid = (lo + hi) >> 1;
    if (batch[mid] < g) lo = mid + 1;
    else hi = mid;
  }
  gstart[g] = lo;
}

__global__ __launch_bounds__(128) void k_pool(const ushort_t* __restrict__ H,
                                              const int* __restrict__ gstart,
                                              float* __restrict__ pooled, int g_count) {
  int g = blockIdx.x >> 4;
  int c = blockIdx.x & 15;
  int s = gstart[g], e = gstart[g + 1];
  int len = e - s;
  int chunk = (len + 15) >> 4;
  int ns = s + c * chunk;
  int ne = min(ns + chunk, e);
  float acc = 0.f;
  for (int i = ns; i < ne; ++i) acc += bf2f(H[(size_t)i * FDIM + threadIdx.x]);
  atomicAdd(&pooled[g * FDIM + threadIdx.x], acc);
}

__global__ __launch_bounds__(192) void k_final(const float* __restrict__ pooled,
                                               const int* __restrict__ gstart,
                                               const float* __restrict__ Wc,
                                               const float* __restrict__ bc,
                                               float* __restrict__ out, int g_count) {
  int t = threadIdx.x;
  if (t >= g_count * 3) return;
  int g = t / 3, c = t % 3;
  int cnt = gstart[g + 1] - gstart[g];
  float inv = 1.0f / (float)max(cnt, 1);
  float acc = bc[c];
#pragma unroll 8
  for (int k = 0; k < FDIM; ++k) acc += pooled[g * FDIM + k] * inv * Wc[k * 3 + c];
  out[g * 3 + c] = acc;
}

// ---------------- host ----------------

extern "C" void kernel_launch(void* const* d_in, const int* in_sizes, int n_in,
                              void* d_out, int out_size, void* d_ws, size_t ws_size,
                              hipStream_t stream) {
  const float* x = (const float*)d_in[0];
  const int* edge = (const int*)d_in[1];
  const int* batch = (const int*)d_in[2];
  const float* W1 = (const float*)d_in[3];
  const float* b1 = (const float*)d_in[4];
  const float* W2 = (const float*)d_in[5];
  const float* b2 = (const float*)d_in[6];
  const float* W3 = (const float*)d_in[7];
  const float* b3 = (const float*)d_in[8];
  const float* Wc = (const float*)d_in[9];
  const float* bc = (const float*)d_in[10];
  float* out = (float*)d_out;

  const int N = in_sizes[0] / FDIM;
  const int E = in_sizes[1] / 2;
  const int G = out_size / 3;
  const int* src = edge;
  const int* dst = edge + E;

  const int NCH = (E + CHUNK - 1) / CHUNK;
  const int NB = (N + (1 << BSHIFT) - 1) >> BSHIFT;

  char* ws = (char*)d_ws;
  size_t off = 0;
  auto carve = [&](size_t bytes) -> void* {
    void* p = ws + off;
    off = (off + bytes + 255) & ~(size_t)255;
    return p;
  };
  ushort_t* h0 = (ushort_t*)carve((size_t)N * FDIM * 2);  // row-major bf16
  ushort_t* h1 = (ushort_t*)carve((size_t)N * FDIM * 2);
  int2* colPair = (int2*)carve((size_t)E * 8);
  unsigned* binned = (unsigned*)carve((size_t)E * 4);
  int* chunkHist = (int*)carve((size_t)NCH * NB * 4);
  int* chunkOff = (int*)carve((size_t)NCH * NB * 4);
  int* bucketTotal = (int*)carve((size_t)NB * 4);
  int* bucketBase = (int*)carve((size_t)(NB + 1) * 4);
  int* rowStart = (int*)carve((size_t)N * 4);
  int* deg = (int*)carve((size_t)N * 4);
  float* dis = (float*)carve((size_t)N * 4);
  int* gstart = (int*)carve((size_t)(G + 1) * 4);
  float* pooled = (float*)carve((size_t)G * FDIM * 4);
  ushort_t* wsw = (ushort_t*)carve((size_t)3 * 16384 * 2);  // swizzled bf16 W
  (void)n_in;
  (void)ws_size;

  hipMemsetAsync(pooled, 0, (size_t)G * FDIM * 4, stream);

  k_hist<<<NCH, 256, 0, stream>>>(dst, E, NB, chunkHist);
  k_scan1<<<NB, 512, 0, stream>>>(chunkHist, NCH, NB, chunkOff, bucketTotal);
  k_scan2<<<1, 512, 0, stream>>>(bucketTotal, NB, E, bucketBase);
  k_bin<<<NCH, 256, 0, stream>>>(src, dst, E, NB, chunkHist, chunkOff, bucketBase,
                                 binned);
  k_fill2<<<NB, 256, 0, stream>>>(binned, bucketBase, N, rowStart, deg, dis, colPair);
  k_edgew<<<(E + 255) / 256, 256, 0, stream>>>(colPair, E, dis);
  k_prepw<<<3, 256, 0, stream>>>(W1, W2, W3, wsw);

  int mmb = (N + 127) / 128;
  int aggb = (N + 7) / 8;
  k_mm<0><<<mmb, 256, 0, stream>>>(x, wsw, h0, N);
  k_agg<<<aggb, 256, 0, stream>>>(h0, h1, rowStart, deg, colPair, dis, b1, N);
  k_mm<1><<<mmb, 256, 0, stream>>>(h1, wsw + 16384, h0, N);
  k_agg<<<aggb, 256, 0, stream>>>(h0, h1, rowStart, deg, colPair, dis, b2, N);
  k_mm<1><<<mmb, 256, 0, stream>>>(h1, wsw + 32768, h0, N);
  k_agg<<<aggb, 256, 0, stream>>>(h0, h1, rowStart, deg, colPair, dis, b3, N);

  k_gstart<<<1, 128, 0, stream>>>(batch, N, G, gstart);
  k_pool<<<G * 16, 128, 0, stream>>>(h1, gstart, pooled, G);
  k_final<<<1, 192, 0, stream>>>(pooled, gstart, Wc, bc, out, G);
}